// Round 12
// baseline (193.540 us; speedup 1.0000x reference)
//
#include <hip/hip_runtime.h>
#include <hip/hip_fp16.h>

#define N_NODES 1000000
#define N_EDGES 4000000
#define N_GRAPHS 1024
#define HIDDEN 64

#define G1 1000                // hist/partition blocks (~4/CU)
#define T1 512
#define EPB (N_EDGES / G1)     // 4000 edges per block (exact)
#define EPB4 (EPB / 4)         // 1000 int4 per block
#define BSHIFT 11
#define BSIZE 2048
#define NBK 512                // bucket slots (489 used)
#define NBUCK ((N_NODES + BSIZE - 1) / BSIZE)  // 489

// __builtin_nontemporal_load rejects HIP_vector_type; use clang ext vectors.
typedef int      vi4 __attribute__((ext_vector_type(4)));
typedef unsigned vu4 __attribute__((ext_vector_type(4)));

__device__ __forceinline__ int4 nt_int4(const int4* p) {
    vi4 v = __builtin_nontemporal_load((const vi4*)p);
    return make_int4(v.x, v.y, v.z, v.w);
}
__device__ __forceinline__ uint4 nt_uint4(const uint4* p) {
    vu4 v = __builtin_nontemporal_load((const vu4*)p);
    return make_uint4(v.x, v.y, v.z, v.w);
}

// ---- pass 1: per-block bucket histogram (LDS) + out init ----
__global__ __launch_bounds__(T1) void k_hist(const int4* __restrict__ col4,
                                             int* __restrict__ part,
                                             float* __restrict__ out,
                                             const float* __restrict__ b2) {
    __shared__ int h[NBK];
    int t = threadIdx.x, blk = blockIdx.x;
    for (int i = t; i < NBK; i += T1) h[i] = 0;
    int gid = blk * T1 + t;
    if (gid < N_GRAPHS) out[gid] = b2[0];
    __syncthreads();
    int b0 = blk * EPB4;
    for (int i = t; i < EPB4; i += T1) {
        int4 c = nt_int4(col4 + b0 + i);
        atomicAdd(&h[((unsigned)c.x) >> BSHIFT], 1);
        atomicAdd(&h[((unsigned)c.y) >> BSHIFT], 1);
        atomicAdd(&h[((unsigned)c.z) >> BSHIFT], 1);
        atomicAdd(&h[((unsigned)c.w) >> BSHIFT], 1);
    }
    __syncthreads();
    for (int i = t; i < NBK; i += T1) part[blk * NBK + i] = h[i];
}

// ---- pass 2a: per-bucket-column exclusive prefix over the G1 blocks ----
__global__ __launch_bounds__(1024) void k_colscan(int* __restrict__ part,
                                                  int* __restrict__ ecnt) {
    int b = blockIdx.x;     // bucket column
    int t = threadIdx.x;    // 0..1023 (G1=1000 used)
    __shared__ int a[1024];
    int v = (t < G1) ? part[t * NBK + b] : 0;
    a[t] = v;
    __syncthreads();
    for (int o = 1; o < 1024; o <<= 1) {
        int u = (t >= o) ? a[t - o] : 0;
        __syncthreads();
        a[t] += u;
        __syncthreads();
    }
    if (t < G1) part[t * NBK + b] = a[t] - v;   // exclusive prefix within column
    if (t == 1023) ecnt[b] = a[1023];           // column total
}

// ---- pass 2b: aligned exclusive scan of bucket totals -> ebase ----
__global__ __launch_bounds__(NBK) void k_bscan(const int* __restrict__ ecnt,
                                               int* __restrict__ ebase) {
    __shared__ int sc[NBK];
    int b = threadIdx.x;
    int run4 = (ecnt[b] + 3) & ~3;   // pad bucket to x4 elems (16B align)
    sc[b] = run4;
    __syncthreads();
    for (int o = 1; o < NBK; o <<= 1) {
        int v = (b >= o) ? sc[b - o] : 0;
        __syncthreads();
        sc[b] += v;
        __syncthreads();
    }
    ebase[b] = sc[b] - run4;
}

// ---- pass 3: partition edges, packed (colLocal<<20 | row) ----
__global__ __launch_bounds__(T1) void k_part(const int4* __restrict__ row4,
                                             const int4* __restrict__ col4,
                                             const int* __restrict__ part,
                                             const int* __restrict__ ebase,
                                             unsigned* __restrict__ epair) {
    __shared__ int cur[NBK];
    int t = threadIdx.x, blk = blockIdx.x;
    for (int i = t; i < NBK; i += T1) cur[i] = part[blk * NBK + i] + ebase[i];
    __syncthreads();
    int b0 = blk * EPB4;
    for (int i = t; i < EPB4; i += T1) {
        int4 c = nt_int4(col4 + b0 + i);
        int4 r = nt_int4(row4 + b0 + i);
        int cc[4] = {c.x, c.y, c.z, c.w};
        int rr[4] = {r.x, r.y, r.z, r.w};
        #pragma unroll
        for (int k = 0; k < 4; ++k) {
            int b = ((unsigned)cc[k]) >> BSHIFT;
            int pos = atomicAdd(&cur[b], 1);
            epair[pos] = ((unsigned)(cc[k] & (BSIZE - 1)) << 20) | (unsigned)rr[k];
        }
    }
}

// ---- pass 4: per-bucket degree (LDS) -> dis (f32), xd (fp16x4) ----
__global__ __launch_bounds__(1024) void k_deg2(const unsigned* __restrict__ epair,
                                               const int* __restrict__ ebase,
                                               const int* __restrict__ ecnt,
                                               const float4* __restrict__ x,
                                               float* __restrict__ dis,
                                               uint2* __restrict__ xdh) {
    __shared__ int deg[BSIZE];   // 8 KB
    int t = threadIdx.x, b = blockIdx.x;
    for (int i = t; i < BSIZE; i += 1024) deg[i] = 1;   // self-loop
    __syncthreads();
    int ne = ecnt[b];
    const unsigned* ep = epair + ebase[b];   // 16B-aligned
    int ne4 = ne & ~3;
    for (int i = 4 * t; i < ne4; i += 4096) {
        uint4 u = nt_uint4((const uint4*)(ep + i));
        atomicAdd(&deg[u.x >> 20], 1);
        atomicAdd(&deg[u.y >> 20], 1);
        atomicAdd(&deg[u.z >> 20], 1);
        atomicAdd(&deg[u.w >> 20], 1);
    }
    for (int i = ne4 + t; i < ne; i += 1024) atomicAdd(&deg[ep[i] >> 20], 1);
    __syncthreads();
    int n0 = b << BSHIFT;
    for (int i = t; i < BSIZE; i += 1024) {
        int node = n0 + i;
        if (node < N_NODES) {
            float d = rsqrtf((float)deg[i]);
            dis[node] = d;
            float4 xv = x[node];
            __half2 h01 = __floats2half2_rn(xv.x * d, xv.y * d);
            __half2 h23 = __floats2half2_rn(xv.z * d, xv.w * d);
            uint2 pk;
            pk.x = *(unsigned*)&h01;
            pk.y = *(unsigned*)&h23;
            xdh[node] = pk;
        }
    }
}

// ---- pass 5: per-bucket gather + LDS accumulate -> sbuf ----
__device__ __forceinline__ void acc_edge(unsigned u, uint2 p, float* sf) {
    int loc = u >> 20;
    __half2 h01 = *(__half2*)&p.x;
    __half2 h23 = *(__half2*)&p.y;
    float2 f01 = __half22float2(h01);
    float2 f23 = __half22float2(h23);
    float* sp = sf + loc * 5;        // stride 5: conflict-free spread
    atomicAdd(sp + 0, f01.x);
    atomicAdd(sp + 1, f01.y);
    atomicAdd(sp + 2, f23.x);
    atomicAdd(sp + 3, f23.y);
}

__global__ __launch_bounds__(1024) void k_acc(const unsigned* __restrict__ epair,
                                              const int* __restrict__ ebase,
                                              const int* __restrict__ ecnt,
                                              const uint2* __restrict__ xdh,
                                              float4* __restrict__ sbuf) {
    __shared__ float sf[BSIZE * 5];   // 40 KB
    int t = threadIdx.x, b = blockIdx.x;
    for (int i = t; i < BSIZE * 5; i += 1024) sf[i] = 0.f;
    __syncthreads();
    int ne = ecnt[b];
    const unsigned* ep = epair + ebase[b];   // 16B-aligned
    int ne4 = ne & ~3;
    for (int i = 4 * t; i < ne4; i += 4096) {
        unsigned u0 = ep[i], u1 = ep[i + 1], u2 = ep[i + 2], u3 = ep[i + 3];
        uint2 p0 = xdh[u0 & 0xFFFFFu];
        uint2 p1 = xdh[u1 & 0xFFFFFu];
        uint2 p2 = xdh[u2 & 0xFFFFFu];
        uint2 p3 = xdh[u3 & 0xFFFFFu];
        acc_edge(u0, p0, sf);
        acc_edge(u1, p1, sf);
        acc_edge(u2, p2, sf);
        acc_edge(u3, p3, sf);
    }
    for (int i = ne4 + t; i < ne; i += 1024) {
        unsigned u = ep[i];
        acc_edge(u, xdh[u & 0xFFFFFu], sf);
    }
    __syncthreads();
    int n0 = b << BSHIFT;
    for (int i = t; i < BSIZE; i += 1024) {
        int node = n0 + i;
        if (node < N_NODES) {
            const float* q = sf + i * 5;
            sbuf[node] = make_float4(q[0], q[1], q[2], q[3]);
        }
    }
}

// ---- pass 6: node-parallel MLP + ELU + pool ----
__global__ __launch_bounds__(256) void k_mlp(const float4* __restrict__ sbuf,
                                             const uint2* __restrict__ xdh,
                                             const float* __restrict__ dis,
                                             const int* __restrict__ batch,
                                             const float* __restrict__ W1,
                                             const float* __restrict__ b1,
                                             const float* __restrict__ W2,
                                             float* __restrict__ out) {
    int n = blockIdx.x * blockDim.x + threadIdx.x;
    bool valid = n < N_NODES;
    float acc = 0.f;
    int g = -1;
    if (valid) {
        float4 sv = sbuf[n];
        uint2 p = xdh[n];
        __half2 h01 = *(__half2*)&p.x;
        __half2 h23 = *(__half2*)&p.y;
        float2 f01 = __half22float2(h01);
        float2 f23 = __half22float2(h23);
        float d = dis[n];
        float u0 = d * (sv.x + f01.x);
        float u1 = d * (sv.y + f01.y);
        float u2 = d * (sv.z + f23.x);
        float u3 = d * (sv.w + f23.y);
        g = batch[n];
        #pragma unroll
        for (int k = 0; k < HIDDEN; ++k) {
            float t = fmaf(u0, W1[k],
                      fmaf(u1, W1[HIDDEN + k],
                      fmaf(u2, W1[2 * HIDDEN + k],
                      fmaf(u3, W1[3 * HIDDEN + k], b1[k]))));
            float h = t > 0.f ? t : (__expf(t) - 1.f);
            acc = fmaf(h, W2[k], acc);
        }
    }
    unsigned long long rem = __ballot(valid);
    while (rem) {
        int leader = __ffsll(rem) - 1;
        int gl = __shfl(g, leader);
        bool mine = valid && (g == gl);
        unsigned long long mask = __ballot(mine);
        float v = mine ? acc : 0.f;
        #pragma unroll
        for (int o = 32; o; o >>= 1) v += __shfl_xor(v, o);
        if ((int)(threadIdx.x & 63) == leader) unsafeAtomicAdd(&out[gl], v);
        rem &= ~mask;
    }
}

// ---------------- fallback: atomic-scatter path (small ws) ----------------
__global__ __launch_bounds__(256) void k_init(int* __restrict__ deg, float4* __restrict__ s,
                                              float* __restrict__ out, const float* __restrict__ b2) {
    int i = blockIdx.x * blockDim.x + threadIdx.x;
    if (i < N_NODES) { deg[i] = 1; s[i] = make_float4(0.f, 0.f, 0.f, 0.f); }
    if (i < N_GRAPHS) out[i] = b2[0];
}
__global__ __launch_bounds__(256) void k_deg(const int* __restrict__ col, int* __restrict__ deg) {
    int e = blockIdx.x * blockDim.x + threadIdx.x;
    if (e < N_EDGES) atomicAdd(&deg[col[e]], 1);
}
__global__ __launch_bounds__(256) void k_dis(const int* __restrict__ deg, float* __restrict__ dis) {
    int i = blockIdx.x * blockDim.x + threadIdx.x;
    if (i < N_NODES) dis[i] = rsqrtf((float)deg[i]);
}
__global__ __launch_bounds__(256) void k_scatter(const int* __restrict__ row, const int* __restrict__ col,
                                                 const float4* __restrict__ x, const float* __restrict__ dis,
                                                 float* __restrict__ s) {
    int e = blockIdx.x * blockDim.x + threadIdx.x;
    if (e >= N_EDGES) return;
    int j = row[e], i = col[e];
    float dj = dis[j];
    float4 xj = x[j];
    float* sp = s + 4ll * (long long)i;
    unsafeAtomicAdd(sp + 0, xj.x * dj);
    unsafeAtomicAdd(sp + 1, xj.y * dj);
    unsafeAtomicAdd(sp + 2, xj.z * dj);
    unsafeAtomicAdd(sp + 3, xj.w * dj);
}
__global__ __launch_bounds__(256) void k_node(const float4* __restrict__ x, const float4* __restrict__ s,
                                              const float* __restrict__ dis, const int* __restrict__ batch,
                                              const float* __restrict__ W1, const float* __restrict__ b1,
                                              const float* __restrict__ W2, float* __restrict__ out) {
    int n = blockIdx.x * blockDim.x + threadIdx.x;
    bool valid = n < N_NODES;
    float acc = 0.f; int g = -1;
    if (valid) {
        float4 xn = x[n], sn = s[n];
        float di = dis[n], inv = di * di;
        float u0 = di * sn.x + inv * xn.x, u1 = di * sn.y + inv * xn.y;
        float u2 = di * sn.z + inv * xn.z, u3 = di * sn.w + inv * xn.w;
        g = batch[n];
        #pragma unroll
        for (int k = 0; k < HIDDEN; ++k) {
            float t = fmaf(u0, W1[k], fmaf(u1, W1[HIDDEN + k],
                      fmaf(u2, W1[2 * HIDDEN + k], fmaf(u3, W1[3 * HIDDEN + k], b1[k]))));
            float h = t > 0.f ? t : expm1f(t);
            acc = fmaf(h, W2[k], acc);
        }
    }
    unsigned long long rem = __ballot(valid);
    while (rem) {
        int leader = __ffsll(rem) - 1;
        int gl = __shfl(g, leader);
        bool mine = valid && (g == gl);
        unsigned long long mask = __ballot(mine);
        float v = mine ? acc : 0.f;
        #pragma unroll
        for (int o = 32; o; o >>= 1) v += __shfl_xor(v, o);
        if ((int)(threadIdx.x & 63) == leader) unsafeAtomicAdd(&out[gl], v);
        rem &= ~mask;
    }
}

extern "C" void kernel_launch(void* const* d_in, const int* in_sizes, int n_in,
                              void* d_out, int out_size, void* d_ws, size_t ws_size,
                              hipStream_t stream) {
    const float* x   = (const float*)d_in[0];
    const float* W1  = (const float*)d_in[1];
    const float* b1  = (const float*)d_in[2];
    const float* W2  = (const float*)d_in[3];
    const float* b2  = (const float*)d_in[4];
    const int*   ei  = (const int*)d_in[5];
    const int*   bat = (const int*)d_in[6];
    float* out = (float*)d_out;

    const int* row = ei;
    const int* col = ei + N_EDGES;
    char* ws = (char*)d_ws;

    // ws layout: ~46.3 MB
    size_t o_ep   = 0;                                        // uint[E + 4*NBK pad]
    size_t o_sb   = o_ep + (size_t)(N_EDGES + 4 * NBK) * 4;   // float4[N] 16 MB
    size_t o_xdh  = o_sb + (size_t)N_NODES * 16;              // uint2[N]   8 MB
    size_t o_dis  = o_xdh + (size_t)N_NODES * 8;              // float[N]   4 MB
    size_t o_part = o_dis + (size_t)N_NODES * 4;              // int[G1*NBK] 2 MB
    size_t o_eb   = o_part + (size_t)G1 * NBK * 4;
    size_t o_ec   = o_eb + NBK * 4;
    size_t need   = o_ec + NBK * 4;

    if (ws_size >= need) {
        unsigned* epair = (unsigned*)(ws + o_ep);
        float4*   sbuf  = (float4*)(ws + o_sb);
        uint2*    xdh   = (uint2*)(ws + o_xdh);
        float*    dis   = (float*)(ws + o_dis);
        int*      part  = (int*)(ws + o_part);
        int*      ebase = (int*)(ws + o_eb);
        int*      ecnt  = (int*)(ws + o_ec);

        k_hist<<<G1, T1, 0, stream>>>((const int4*)col, part, out, b2);
        k_colscan<<<NBK, 1024, 0, stream>>>(part, ecnt);
        k_bscan<<<1, NBK, 0, stream>>>(ecnt, ebase);
        k_part<<<G1, T1, 0, stream>>>((const int4*)row, (const int4*)col, part, ebase, epair);
        k_deg2<<<NBUCK, 1024, 0, stream>>>(epair, ebase, ecnt, (const float4*)x, dis, xdh);
        k_acc<<<NBUCK, 1024, 0, stream>>>(epair, ebase, ecnt, xdh, sbuf);
        k_mlp<<<(N_NODES + 255) / 256, 256, 0, stream>>>(sbuf, xdh, dis, bat, W1, b1, W2, out);
    } else {
        int nb_n = (N_NODES + 255) / 256;
        int nb_e = (N_EDGES + 255) / 256;
        int*    deg = (int*)(ws);
        float*  dis = (float*)(ws + (size_t)N_NODES * 4);
        float*  s   = (float*)(ws + (size_t)N_NODES * 8);
        float4* s4  = (float4*)s;
        k_init<<<nb_n, 256, 0, stream>>>(deg, s4, out, b2);
        k_deg<<<nb_e, 256, 0, stream>>>(col, deg);
        k_dis<<<nb_n, 256, 0, stream>>>(deg, dis);
        k_scatter<<<nb_e, 256, 0, stream>>>(row, col, (const float4*)x, dis, s);
        k_node<<<nb_n, 256, 0, stream>>>((const float4*)x, s4, dis, bat, W1, b1, W2, out);
    }
}

// Round 13
// 183.427 us; speedup vs baseline: 1.0551x; 1.0551x over previous
//
#include <hip/hip_runtime.h>
#include <hip/hip_fp16.h>

#define N_NODES 1000000
#define N_EDGES 4000000
#define N_GRAPHS 1024
#define HIDDEN 64

#define G1 250                 // hist/partition blocks
#define T1 512
#define EPB (N_EDGES / G1)     // 16000 edges per block (exact)
#define EPB4 (EPB / 4)         // 4000 int4 per block
#define BSHIFT 11
#define BSIZE 2048
#define NBK 512                // bucket slots (489 used)
#define NBUCK ((N_NODES + BSIZE - 1) / BSIZE)  // 489

// __builtin_nontemporal_load rejects HIP_vector_type; use clang ext vectors.
typedef int      vi4 __attribute__((ext_vector_type(4)));
typedef unsigned vu4 __attribute__((ext_vector_type(4)));

__device__ __forceinline__ int4 nt_int4(const int4* p) {
    vi4 v = __builtin_nontemporal_load((const vi4*)p);
    return make_int4(v.x, v.y, v.z, v.w);
}
__device__ __forceinline__ uint4 nt_uint4(const uint4* p) {
    vu4 v = __builtin_nontemporal_load((const vu4*)p);
    return make_uint4(v.x, v.y, v.z, v.w);
}

// ---- pass 1: per-block bucket histogram (LDS) + out init ----
__global__ __launch_bounds__(T1) void k_hist(const int4* __restrict__ col4,
                                             int* __restrict__ part,
                                             float* __restrict__ out,
                                             const float* __restrict__ b2) {
    __shared__ int h[NBK];
    int t = threadIdx.x, blk = blockIdx.x;
    for (int i = t; i < NBK; i += T1) h[i] = 0;
    int gid = blk * T1 + t;
    if (gid < N_GRAPHS) out[gid] = b2[0];
    __syncthreads();
    int b0 = blk * EPB4;
    for (int i = t; i < EPB4; i += T1) {
        int4 c = nt_int4(col4 + b0 + i);
        atomicAdd(&h[((unsigned)c.x) >> BSHIFT], 1);
        atomicAdd(&h[((unsigned)c.y) >> BSHIFT], 1);
        atomicAdd(&h[((unsigned)c.z) >> BSHIFT], 1);
        atomicAdd(&h[((unsigned)c.w) >> BSHIFT], 1);
    }
    __syncthreads();
    for (int i = t; i < NBK; i += T1) part[blk * NBK + i] = h[i];
}

// ---- pass 2a: per-bucket-column exclusive prefix over the G1 blocks ----
__global__ __launch_bounds__(256) void k_colscan(int* __restrict__ part,
                                                 int* __restrict__ ecnt) {
    int b = blockIdx.x;     // bucket column
    int t = threadIdx.x;    // 0..255 (G1=250 used)
    __shared__ int a[256];
    int v = (t < G1) ? part[t * NBK + b] : 0;
    a[t] = v;
    __syncthreads();
    for (int o = 1; o < 256; o <<= 1) {
        int u = (t >= o) ? a[t - o] : 0;
        __syncthreads();
        a[t] += u;
        __syncthreads();
    }
    if (t < G1) part[t * NBK + b] = a[t] - v;   // exclusive prefix within column
    if (t == 255) ecnt[b] = a[255];             // column total
}

// ---- pass 2b: aligned exclusive scan of bucket totals -> ebase ----
__global__ __launch_bounds__(NBK) void k_bscan(const int* __restrict__ ecnt,
                                               int* __restrict__ ebase) {
    __shared__ int sc[NBK];
    int b = threadIdx.x;
    int run4 = (ecnt[b] + 3) & ~3;   // pad bucket to x4 elems (16B align)
    sc[b] = run4;
    __syncthreads();
    for (int o = 1; o < NBK; o <<= 1) {
        int v = (b >= o) ? sc[b - o] : 0;
        __syncthreads();
        sc[b] += v;
        __syncthreads();
    }
    ebase[b] = sc[b] - run4;
}

// ---- pass 3: partition edges, packed (colLocal<<20 | row) ----
__global__ __launch_bounds__(T1) void k_part(const int4* __restrict__ row4,
                                             const int4* __restrict__ col4,
                                             const int* __restrict__ part,
                                             const int* __restrict__ ebase,
                                             unsigned* __restrict__ epair) {
    __shared__ int cur[NBK];
    int t = threadIdx.x, blk = blockIdx.x;
    for (int i = t; i < NBK; i += T1) cur[i] = part[blk * NBK + i] + ebase[i];
    __syncthreads();
    int b0 = blk * EPB4;
    for (int i = t; i < EPB4; i += T1) {
        int4 c = nt_int4(col4 + b0 + i);
        int4 r = nt_int4(row4 + b0 + i);
        int cc[4] = {c.x, c.y, c.z, c.w};
        int rr[4] = {r.x, r.y, r.z, r.w};
        #pragma unroll
        for (int k = 0; k < 4; ++k) {
            int b = ((unsigned)cc[k]) >> BSHIFT;
            int pos = atomicAdd(&cur[b], 1);
            epair[pos] = ((unsigned)(cc[k] & (BSIZE - 1)) << 20) | (unsigned)rr[k];
        }
    }
}

// ---- pass 4: per-bucket degree (LDS) -> dis (f32), xd (fp16x4) ----
__global__ __launch_bounds__(1024) void k_deg2(const unsigned* __restrict__ epair,
                                               const int* __restrict__ ebase,
                                               const int* __restrict__ ecnt,
                                               const float4* __restrict__ x,
                                               float* __restrict__ dis,
                                               uint2* __restrict__ xdh) {
    __shared__ int deg[BSIZE];   // 8 KB
    int t = threadIdx.x, b = blockIdx.x;
    for (int i = t; i < BSIZE; i += 1024) deg[i] = 1;   // self-loop
    __syncthreads();
    int ne = ecnt[b];
    const unsigned* ep = epair + ebase[b];   // 16B-aligned
    int ne4 = ne & ~3;
    for (int i = 4 * t; i < ne4; i += 4096) {
        uint4 u = nt_uint4((const uint4*)(ep + i));
        atomicAdd(&deg[u.x >> 20], 1);
        atomicAdd(&deg[u.y >> 20], 1);
        atomicAdd(&deg[u.z >> 20], 1);
        atomicAdd(&deg[u.w >> 20], 1);
    }
    for (int i = ne4 + t; i < ne; i += 1024) atomicAdd(&deg[ep[i] >> 20], 1);
    __syncthreads();
    int n0 = b << BSHIFT;
    for (int i = t; i < BSIZE; i += 1024) {
        int node = n0 + i;
        if (node < N_NODES) {
            float d = rsqrtf((float)deg[i]);
            dis[node] = d;
            float4 xv = x[node];
            __half2 h01 = __floats2half2_rn(xv.x * d, xv.y * d);
            __half2 h23 = __floats2half2_rn(xv.z * d, xv.w * d);
            uint2 pk;
            pk.x = *(unsigned*)&h01;
            pk.y = *(unsigned*)&h23;
            xdh[node] = pk;
        }
    }
}

// ---- pass 5: per-bucket gather + LDS accumulate -> sbuf (fp16x4) ----
__device__ __forceinline__ void acc_edge(unsigned u, uint2 p, float* sf) {
    int loc = u >> 20;
    __half2 h01 = *(__half2*)&p.x;
    __half2 h23 = *(__half2*)&p.y;
    float2 f01 = __half22float2(h01);
    float2 f23 = __half22float2(h23);
    float* sp = sf + loc * 5;        // stride 5: conflict-free spread
    atomicAdd(sp + 0, f01.x);
    atomicAdd(sp + 1, f01.y);
    atomicAdd(sp + 2, f23.x);
    atomicAdd(sp + 3, f23.y);
}

__global__ __launch_bounds__(1024) void k_acc(const unsigned* __restrict__ epair,
                                              const int* __restrict__ ebase,
                                              const int* __restrict__ ecnt,
                                              const uint2* __restrict__ xdh,
                                              uint2* __restrict__ sbuf) {
    __shared__ float sf[BSIZE * 5];   // 40 KB
    int t = threadIdx.x, b = blockIdx.x;
    for (int i = t; i < BSIZE * 5; i += 1024) sf[i] = 0.f;
    __syncthreads();
    int ne = ecnt[b];
    const unsigned* ep = epair + ebase[b];   // 16B-aligned
    int ne4 = ne & ~3;
    for (int i = 4 * t; i < ne4; i += 4096) {
        unsigned u0 = ep[i], u1 = ep[i + 1], u2 = ep[i + 2], u3 = ep[i + 3];
        uint2 p0 = xdh[u0 & 0xFFFFFu];
        uint2 p1 = xdh[u1 & 0xFFFFFu];
        uint2 p2 = xdh[u2 & 0xFFFFFu];
        uint2 p3 = xdh[u3 & 0xFFFFFu];
        acc_edge(u0, p0, sf);
        acc_edge(u1, p1, sf);
        acc_edge(u2, p2, sf);
        acc_edge(u3, p3, sf);
    }
    for (int i = ne4 + t; i < ne; i += 1024) {
        unsigned u = ep[i];
        acc_edge(u, xdh[u & 0xFFFFFu], sf);
    }
    __syncthreads();
    int n0 = b << BSHIFT;
    for (int i = t; i < BSIZE; i += 1024) {
        int node = n0 + i;
        if (node < N_NODES) {
            const float* q = sf + i * 5;
            __half2 s01 = __floats2half2_rn(q[0], q[1]);
            __half2 s23 = __floats2half2_rn(q[2], q[3]);
            uint2 pk;
            pk.x = *(unsigned*)&s01;
            pk.y = *(unsigned*)&s23;
            sbuf[node] = pk;
        }
    }
}

// ---- pass 6: node-parallel MLP + ELU + pool ----
__global__ __launch_bounds__(256) void k_mlp(const uint2* __restrict__ sbuf,
                                             const uint2* __restrict__ xdh,
                                             const float* __restrict__ dis,
                                             const int* __restrict__ batch,
                                             const float* __restrict__ W1,
                                             const float* __restrict__ b1,
                                             const float* __restrict__ W2,
                                             float* __restrict__ out) {
    int n = blockIdx.x * blockDim.x + threadIdx.x;
    bool valid = n < N_NODES;
    float acc = 0.f;
    int g = -1;
    if (valid) {
        uint2 sv = sbuf[n];
        uint2 p = xdh[n];
        float2 s01 = __half22float2(*(__half2*)&sv.x);
        float2 s23 = __half22float2(*(__half2*)&sv.y);
        float2 f01 = __half22float2(*(__half2*)&p.x);
        float2 f23 = __half22float2(*(__half2*)&p.y);
        float d = dis[n];
        float u0 = d * (s01.x + f01.x);
        float u1 = d * (s01.y + f01.y);
        float u2 = d * (s23.x + f23.x);
        float u3 = d * (s23.y + f23.y);
        g = batch[n];
        #pragma unroll
        for (int k = 0; k < HIDDEN; ++k) {
            float t = fmaf(u0, W1[k],
                      fmaf(u1, W1[HIDDEN + k],
                      fmaf(u2, W1[2 * HIDDEN + k],
                      fmaf(u3, W1[3 * HIDDEN + k], b1[k]))));
            float h = t > 0.f ? t : (__expf(t) - 1.f);
            acc = fmaf(h, W2[k], acc);
        }
    }
    unsigned long long rem = __ballot(valid);
    while (rem) {
        int leader = __ffsll(rem) - 1;
        int gl = __shfl(g, leader);
        bool mine = valid && (g == gl);
        unsigned long long mask = __ballot(mine);
        float v = mine ? acc : 0.f;
        #pragma unroll
        for (int o = 32; o; o >>= 1) v += __shfl_xor(v, o);
        if ((int)(threadIdx.x & 63) == leader) unsafeAtomicAdd(&out[gl], v);
        rem &= ~mask;
    }
}

// ---------------- fallback: atomic-scatter path (small ws) ----------------
__global__ __launch_bounds__(256) void k_init(int* __restrict__ deg, float4* __restrict__ s,
                                              float* __restrict__ out, const float* __restrict__ b2) {
    int i = blockIdx.x * blockDim.x + threadIdx.x;
    if (i < N_NODES) { deg[i] = 1; s[i] = make_float4(0.f, 0.f, 0.f, 0.f); }
    if (i < N_GRAPHS) out[i] = b2[0];
}
__global__ __launch_bounds__(256) void k_deg(const int* __restrict__ col, int* __restrict__ deg) {
    int e = blockIdx.x * blockDim.x + threadIdx.x;
    if (e < N_EDGES) atomicAdd(&deg[col[e]], 1);
}
__global__ __launch_bounds__(256) void k_dis(const int* __restrict__ deg, float* __restrict__ dis) {
    int i = blockIdx.x * blockDim.x + threadIdx.x;
    if (i < N_NODES) dis[i] = rsqrtf((float)deg[i]);
}
__global__ __launch_bounds__(256) void k_scatter(const int* __restrict__ row, const int* __restrict__ col,
                                                 const float4* __restrict__ x, const float* __restrict__ dis,
                                                 float* __restrict__ s) {
    int e = blockIdx.x * blockDim.x + threadIdx.x;
    if (e >= N_EDGES) return;
    int j = row[e], i = col[e];
    float dj = dis[j];
    float4 xj = x[j];
    float* sp = s + 4ll * (long long)i;
    unsafeAtomicAdd(sp + 0, xj.x * dj);
    unsafeAtomicAdd(sp + 1, xj.y * dj);
    unsafeAtomicAdd(sp + 2, xj.z * dj);
    unsafeAtomicAdd(sp + 3, xj.w * dj);
}
__global__ __launch_bounds__(256) void k_node(const float4* __restrict__ x, const float4* __restrict__ s,
                                              const float* __restrict__ dis, const int* __restrict__ batch,
                                              const float* __restrict__ W1, const float* __restrict__ b1,
                                              const float* __restrict__ W2, float* __restrict__ out) {
    int n = blockIdx.x * blockDim.x + threadIdx.x;
    bool valid = n < N_NODES;
    float acc = 0.f; int g = -1;
    if (valid) {
        float4 xn = x[n], sn = s[n];
        float di = dis[n], inv = di * di;
        float u0 = di * sn.x + inv * xn.x, u1 = di * sn.y + inv * xn.y;
        float u2 = di * sn.z + inv * xn.z, u3 = di * sn.w + inv * xn.w;
        g = batch[n];
        #pragma unroll
        for (int k = 0; k < HIDDEN; ++k) {
            float t = fmaf(u0, W1[k], fmaf(u1, W1[HIDDEN + k],
                      fmaf(u2, W1[2 * HIDDEN + k], fmaf(u3, W1[3 * HIDDEN + k], b1[k]))));
            float h = t > 0.f ? t : expm1f(t);
            acc = fmaf(h, W2[k], acc);
        }
    }
    unsigned long long rem = __ballot(valid);
    while (rem) {
        int leader = __ffsll(rem) - 1;
        int gl = __shfl(g, leader);
        bool mine = valid && (g == gl);
        unsigned long long mask = __ballot(mine);
        float v = mine ? acc : 0.f;
        #pragma unroll
        for (int o = 32; o; o >>= 1) v += __shfl_xor(v, o);
        if ((int)(threadIdx.x & 63) == leader) unsafeAtomicAdd(&out[gl], v);
        rem &= ~mask;
    }
}

extern "C" void kernel_launch(void* const* d_in, const int* in_sizes, int n_in,
                              void* d_out, int out_size, void* d_ws, size_t ws_size,
                              hipStream_t stream) {
    const float* x   = (const float*)d_in[0];
    const float* W1  = (const float*)d_in[1];
    const float* b1  = (const float*)d_in[2];
    const float* W2  = (const float*)d_in[3];
    const float* b2  = (const float*)d_in[4];
    const int*   ei  = (const int*)d_in[5];
    const int*   bat = (const int*)d_in[6];
    float* out = (float*)d_out;

    const int* row = ei;
    const int* col = ei + N_EDGES;
    char* ws = (char*)d_ws;

    // ws layout: ~37 MB
    size_t o_ep   = 0;                                        // uint[E + 4*NBK pad]
    size_t o_sb   = o_ep + (size_t)(N_EDGES + 4 * NBK) * 4;   // uint2[N]   8 MB
    size_t o_xdh  = o_sb + (size_t)N_NODES * 8;               // uint2[N]   8 MB
    size_t o_dis  = o_xdh + (size_t)N_NODES * 8;              // float[N]   4 MB
    size_t o_part = o_dis + (size_t)N_NODES * 4;              // int[G1*NBK] 512 KB
    size_t o_eb   = o_part + (size_t)G1 * NBK * 4;
    size_t o_ec   = o_eb + NBK * 4;
    size_t need   = o_ec + NBK * 4;

    if (ws_size >= need) {
        unsigned* epair = (unsigned*)(ws + o_ep);
        uint2*    sbuf  = (uint2*)(ws + o_sb);
        uint2*    xdh   = (uint2*)(ws + o_xdh);
        float*    dis   = (float*)(ws + o_dis);
        int*      part  = (int*)(ws + o_part);
        int*      ebase = (int*)(ws + o_eb);
        int*      ecnt  = (int*)(ws + o_ec);

        k_hist<<<G1, T1, 0, stream>>>((const int4*)col, part, out, b2);
        k_colscan<<<NBK, 256, 0, stream>>>(part, ecnt);
        k_bscan<<<1, NBK, 0, stream>>>(ecnt, ebase);
        k_part<<<G1, T1, 0, stream>>>((const int4*)row, (const int4*)col, part, ebase, epair);
        k_deg2<<<NBUCK, 1024, 0, stream>>>(epair, ebase, ecnt, (const float4*)x, dis, xdh);
        k_acc<<<NBUCK, 1024, 0, stream>>>(epair, ebase, ecnt, xdh, sbuf);
        k_mlp<<<(N_NODES + 255) / 256, 256, 0, stream>>>(sbuf, xdh, dis, bat, W1, b1, W2, out);
    } else {
        int nb_n = (N_NODES + 255) / 256;
        int nb_e = (N_EDGES + 255) / 256;
        int*    deg = (int*)(ws);
        float*  dis = (float*)(ws + (size_t)N_NODES * 4);
        float*  s   = (float*)(ws + (size_t)N_NODES * 8);
        float4* s4  = (float4*)s;
        k_init<<<nb_n, 256, 0, stream>>>(deg, s4, out, b2);
        k_deg<<<nb_e, 256, 0, stream>>>(col, deg);
        k_dis<<<nb_n, 256, 0, stream>>>(deg, dis);
        k_scatter<<<nb_e, 256, 0, stream>>>(row, col, (const float4*)x, dis, s);
        k_node<<<nb_n, 256, 0, stream>>>((const float4*)x, s4, dis, bat, W1, b1, W2, out);
    }
}

// Round 14
// 176.269 us; speedup vs baseline: 1.0980x; 1.0406x over previous
//
#include <hip/hip_runtime.h>
#include <hip/hip_fp16.h>

#define N_NODES 1000000
#define N_EDGES 4000000
#define N_GRAPHS 1024
#define HIDDEN 64

#define G1 250                 // hist/partition blocks
#define T1 512
#define EPB (N_EDGES / G1)     // 16000 edges per block (exact)
#define EPB4 (EPB / 4)         // 4000 int4 per block
#define BSHIFT 11
#define BSIZE 2048
#define NBK 512                // bucket slots (489 used)
#define NBUCK ((N_NODES + BSIZE - 1) / BSIZE)  // 489

// __builtin_nontemporal_load rejects HIP_vector_type; use clang ext vectors.
typedef int      vi4 __attribute__((ext_vector_type(4)));
typedef unsigned vu4 __attribute__((ext_vector_type(4)));

__device__ __forceinline__ int4 nt_int4(const int4* p) {
    vi4 v = __builtin_nontemporal_load((const vi4*)p);
    return make_int4(v.x, v.y, v.z, v.w);
}
__device__ __forceinline__ uint4 nt_uint4(const uint4* p) {
    vu4 v = __builtin_nontemporal_load((const vu4*)p);
    return make_uint4(v.x, v.y, v.z, v.w);
}

// ---- pass 1: per-block bucket histogram (LDS) + out init ----
__global__ __launch_bounds__(T1) void k_hist(const int4* __restrict__ col4,
                                             int* __restrict__ part,
                                             float* __restrict__ out,
                                             const float* __restrict__ b2) {
    __shared__ int h[NBK];
    int t = threadIdx.x, blk = blockIdx.x;
    for (int i = t; i < NBK; i += T1) h[i] = 0;
    int gid = blk * T1 + t;
    if (gid < N_GRAPHS) out[gid] = b2[0];
    __syncthreads();
    int b0 = blk * EPB4;
    for (int i = t; i < EPB4; i += T1) {
        int4 c = nt_int4(col4 + b0 + i);
        atomicAdd(&h[((unsigned)c.x) >> BSHIFT], 1);
        atomicAdd(&h[((unsigned)c.y) >> BSHIFT], 1);
        atomicAdd(&h[((unsigned)c.z) >> BSHIFT], 1);
        atomicAdd(&h[((unsigned)c.w) >> BSHIFT], 1);
    }
    __syncthreads();
    for (int i = t; i < NBK; i += T1) part[blk * NBK + i] = h[i];
}

// ---- pass 2a: per-bucket-column exclusive prefix over the G1 blocks ----
__global__ __launch_bounds__(256) void k_colscan(int* __restrict__ part,
                                                 int* __restrict__ ecnt) {
    int b = blockIdx.x;     // bucket column
    int t = threadIdx.x;    // 0..255 (G1=250 used)
    __shared__ int a[256];
    int v = (t < G1) ? part[t * NBK + b] : 0;
    a[t] = v;
    __syncthreads();
    for (int o = 1; o < 256; o <<= 1) {
        int u = (t >= o) ? a[t - o] : 0;
        __syncthreads();
        a[t] += u;
        __syncthreads();
    }
    if (t < G1) part[t * NBK + b] = a[t] - v;   // exclusive prefix within column
    if (t == 255) ecnt[b] = a[255];             // column total
}

// ---- pass 2b: aligned exclusive scan of bucket totals -> ebase ----
__global__ __launch_bounds__(NBK) void k_bscan(const int* __restrict__ ecnt,
                                               int* __restrict__ ebase) {
    __shared__ int sc[NBK];
    int b = threadIdx.x;
    int run4 = (ecnt[b] + 3) & ~3;   // pad bucket to x4 elems (16B align)
    sc[b] = run4;
    __syncthreads();
    for (int o = 1; o < NBK; o <<= 1) {
        int v = (b >= o) ? sc[b - o] : 0;
        __syncthreads();
        sc[b] += v;
        __syncthreads();
    }
    ebase[b] = sc[b] - run4;
}

// ---- pass 3: partition edges, packed (colLocal<<20 | row) ----
__global__ __launch_bounds__(T1) void k_part(const int4* __restrict__ row4,
                                             const int4* __restrict__ col4,
                                             const int* __restrict__ part,
                                             const int* __restrict__ ebase,
                                             unsigned* __restrict__ epair) {
    __shared__ int cur[NBK];
    int t = threadIdx.x, blk = blockIdx.x;
    for (int i = t; i < NBK; i += T1) cur[i] = part[blk * NBK + i] + ebase[i];
    __syncthreads();
    int b0 = blk * EPB4;
    for (int i = t; i < EPB4; i += T1) {
        int4 c = nt_int4(col4 + b0 + i);
        int4 r = nt_int4(row4 + b0 + i);
        int cc[4] = {c.x, c.y, c.z, c.w};
        int rr[4] = {r.x, r.y, r.z, r.w};
        #pragma unroll
        for (int k = 0; k < 4; ++k) {
            int b = ((unsigned)cc[k]) >> BSHIFT;
            int pos = atomicAdd(&cur[b], 1);
            epair[pos] = ((unsigned)(cc[k] & (BSIZE - 1)) << 20) | (unsigned)rr[k];
        }
    }
}

// ---- pass 4: per-bucket degree (LDS) -> dis (f32), xd (fp16x4) ----
__global__ __launch_bounds__(1024) void k_deg2(const unsigned* __restrict__ epair,
                                               const int* __restrict__ ebase,
                                               const int* __restrict__ ecnt,
                                               const float4* __restrict__ x,
                                               float* __restrict__ dis,
                                               uint2* __restrict__ xdh) {
    __shared__ int deg[BSIZE];   // 8 KB
    int t = threadIdx.x, b = blockIdx.x;
    for (int i = t; i < BSIZE; i += 1024) deg[i] = 1;   // self-loop
    __syncthreads();
    int ne = ecnt[b];
    const unsigned* ep = epair + ebase[b];   // 16B-aligned
    int ne4 = ne & ~3;
    for (int i = 4 * t; i < ne4; i += 4096) {
        uint4 u = nt_uint4((const uint4*)(ep + i));
        atomicAdd(&deg[u.x >> 20], 1);
        atomicAdd(&deg[u.y >> 20], 1);
        atomicAdd(&deg[u.z >> 20], 1);
        atomicAdd(&deg[u.w >> 20], 1);
    }
    for (int i = ne4 + t; i < ne; i += 1024) atomicAdd(&deg[ep[i] >> 20], 1);
    __syncthreads();
    int n0 = b << BSHIFT;
    for (int i = t; i < BSIZE; i += 1024) {
        int node = n0 + i;
        if (node < N_NODES) {
            float d = rsqrtf((float)deg[i]);
            dis[node] = d;
            float4 xv = x[node];
            __half2 h01 = __floats2half2_rn(xv.x * d, xv.y * d);
            __half2 h23 = __floats2half2_rn(xv.z * d, xv.w * d);
            uint2 pk;
            pk.x = *(unsigned*)&h01;
            pk.y = *(unsigned*)&h23;
            xdh[node] = pk;
        }
    }
}

// ---- pass 5: per-bucket gather + LDS accumulate + fused MLP/ELU/pool ----
__device__ __forceinline__ void acc_edge(unsigned u, uint2 p, float* sf) {
    int loc = u >> 20;
    __half2 h01 = *(__half2*)&p.x;
    __half2 h23 = *(__half2*)&p.y;
    float2 f01 = __half22float2(h01);
    float2 f23 = __half22float2(h23);
    float* sp = sf + loc * 5;        // stride 5: conflict-free spread
    atomicAdd(sp + 0, f01.x);
    atomicAdd(sp + 1, f01.y);
    atomicAdd(sp + 2, f23.x);
    atomicAdd(sp + 3, f23.y);
}

__global__ __launch_bounds__(1024) void k_accF(const unsigned* __restrict__ epair,
                                               const int* __restrict__ ebase,
                                               const int* __restrict__ ecnt,
                                               const uint2* __restrict__ xdh,
                                               const float* __restrict__ dis,
                                               const int* __restrict__ batch,
                                               const float* __restrict__ W1,
                                               const float* __restrict__ b1,
                                               const float* __restrict__ W2,
                                               float* __restrict__ out) {
    __shared__ float sf[BSIZE * 5];   // 40 KB
    int t = threadIdx.x, b = blockIdx.x;
    for (int i = t; i < BSIZE * 5; i += 1024) sf[i] = 0.f;
    __syncthreads();
    int ne = ecnt[b];
    const unsigned* ep = epair + ebase[b];   // 16B-aligned
    int ne4 = ne & ~3;
    for (int i = 4 * t; i < ne4; i += 4096) {
        unsigned u0 = ep[i], u1 = ep[i + 1], u2 = ep[i + 2], u3 = ep[i + 3];
        uint2 p0 = xdh[u0 & 0xFFFFFu];
        uint2 p1 = xdh[u1 & 0xFFFFFu];
        uint2 p2 = xdh[u2 & 0xFFFFFu];
        uint2 p3 = xdh[u3 & 0xFFFFFu];
        acc_edge(u0, p0, sf);
        acc_edge(u1, p1, sf);
        acc_edge(u2, p2, sf);
        acc_edge(u3, p3, sf);
    }
    for (int i = ne4 + t; i < ne; i += 1024) {
        unsigned u = ep[i];
        acc_edge(u, xdh[u & 0xFFFFFu], sf);
    }
    __syncthreads();
    // fused MLP + ELU + pool, straight from LDS
    int n0 = b << BSHIFT;
    #pragma unroll
    for (int k = 0; k < BSIZE / 1024; ++k) {   // 2 nodes/thread
        int ln = t + k * 1024;
        int node = n0 + ln;
        bool valid = node < N_NODES;
        float acc = 0.f;
        int g = -1;
        if (valid) {
            const float* sp = sf + ln * 5;
            uint2 p = xdh[node];
            __half2 h01 = *(__half2*)&p.x;
            __half2 h23 = *(__half2*)&p.y;
            float2 f01 = __half22float2(h01);
            float2 f23 = __half22float2(h23);
            float d = dis[node];
            float u0 = d * (sp[0] + f01.x);
            float u1 = d * (sp[1] + f01.y);
            float u2 = d * (sp[2] + f23.x);
            float u3 = d * (sp[3] + f23.y);
            g = batch[node];
            #pragma unroll
            for (int kk = 0; kk < HIDDEN; ++kk) {
                float tt = fmaf(u0, W1[kk],
                           fmaf(u1, W1[HIDDEN + kk],
                           fmaf(u2, W1[2 * HIDDEN + kk],
                           fmaf(u3, W1[3 * HIDDEN + kk], b1[kk]))));
                float h = tt > 0.f ? tt : (__expf(tt) - 1.f);
                acc = fmaf(h, W2[kk], acc);
            }
        }
        unsigned long long rem = __ballot(valid);
        while (rem) {
            int leader = __ffsll(rem) - 1;
            int gl = __shfl(g, leader);
            bool mine = valid && (g == gl);
            unsigned long long mask = __ballot(mine);
            float v = mine ? acc : 0.f;
            #pragma unroll
            for (int o = 32; o; o >>= 1) v += __shfl_xor(v, o);
            if ((int)(t & 63) == leader) unsafeAtomicAdd(&out[gl], v);
            rem &= ~mask;
        }
    }
}

// ---------------- fallback: atomic-scatter path (small ws) ----------------
__global__ __launch_bounds__(256) void k_init(int* __restrict__ deg, float4* __restrict__ s,
                                              float* __restrict__ out, const float* __restrict__ b2) {
    int i = blockIdx.x * blockDim.x + threadIdx.x;
    if (i < N_NODES) { deg[i] = 1; s[i] = make_float4(0.f, 0.f, 0.f, 0.f); }
    if (i < N_GRAPHS) out[i] = b2[0];
}
__global__ __launch_bounds__(256) void k_deg(const int* __restrict__ col, int* __restrict__ deg) {
    int e = blockIdx.x * blockDim.x + threadIdx.x;
    if (e < N_EDGES) atomicAdd(&deg[col[e]], 1);
}
__global__ __launch_bounds__(256) void k_dis(const int* __restrict__ deg, float* __restrict__ dis) {
    int i = blockIdx.x * blockDim.x + threadIdx.x;
    if (i < N_NODES) dis[i] = rsqrtf((float)deg[i]);
}
__global__ __launch_bounds__(256) void k_scatter(const int* __restrict__ row, const int* __restrict__ col,
                                                 const float4* __restrict__ x, const float* __restrict__ dis,
                                                 float* __restrict__ s) {
    int e = blockIdx.x * blockDim.x + threadIdx.x;
    if (e >= N_EDGES) return;
    int j = row[e], i = col[e];
    float dj = dis[j];
    float4 xj = x[j];
    float* sp = s + 4ll * (long long)i;
    unsafeAtomicAdd(sp + 0, xj.x * dj);
    unsafeAtomicAdd(sp + 1, xj.y * dj);
    unsafeAtomicAdd(sp + 2, xj.z * dj);
    unsafeAtomicAdd(sp + 3, xj.w * dj);
}
__global__ __launch_bounds__(256) void k_node(const float4* __restrict__ x, const float4* __restrict__ s,
                                              const float* __restrict__ dis, const int* __restrict__ batch,
                                              const float* __restrict__ W1, const float* __restrict__ b1,
                                              const float* __restrict__ W2, float* __restrict__ out) {
    int n = blockIdx.x * blockDim.x + threadIdx.x;
    bool valid = n < N_NODES;
    float acc = 0.f; int g = -1;
    if (valid) {
        float4 xn = x[n], sn = s[n];
        float di = dis[n], inv = di * di;
        float u0 = di * sn.x + inv * xn.x, u1 = di * sn.y + inv * xn.y;
        float u2 = di * sn.z + inv * xn.z, u3 = di * sn.w + inv * xn.w;
        g = batch[n];
        #pragma unroll
        for (int k = 0; k < HIDDEN; ++k) {
            float t = fmaf(u0, W1[k], fmaf(u1, W1[HIDDEN + k],
                      fmaf(u2, W1[2 * HIDDEN + k], fmaf(u3, W1[3 * HIDDEN + k], b1[k]))));
            float h = t > 0.f ? t : expm1f(t);
            acc = fmaf(h, W2[k], acc);
        }
    }
    unsigned long long rem = __ballot(valid);
    while (rem) {
        int leader = __ffsll(rem) - 1;
        int gl = __shfl(g, leader);
        bool mine = valid && (g == gl);
        unsigned long long mask = __ballot(mine);
        float v = mine ? acc : 0.f;
        #pragma unroll
        for (int o = 32; o; o >>= 1) v += __shfl_xor(v, o);
        if ((int)(threadIdx.x & 63) == leader) unsafeAtomicAdd(&out[gl], v);
        rem &= ~mask;
    }
}

extern "C" void kernel_launch(void* const* d_in, const int* in_sizes, int n_in,
                              void* d_out, int out_size, void* d_ws, size_t ws_size,
                              hipStream_t stream) {
    const float* x   = (const float*)d_in[0];
    const float* W1  = (const float*)d_in[1];
    const float* b1  = (const float*)d_in[2];
    const float* W2  = (const float*)d_in[3];
    const float* b2  = (const float*)d_in[4];
    const int*   ei  = (const int*)d_in[5];
    const int*   bat = (const int*)d_in[6];
    float* out = (float*)d_out;

    const int* row = ei;
    const int* col = ei + N_EDGES;
    char* ws = (char*)d_ws;

    // ws layout: ~28.6 MB
    size_t o_ep   = 0;                                        // uint[E + 4*NBK pad]
    size_t o_xdh  = o_ep + (size_t)(N_EDGES + 4 * NBK) * 4;   // uint2[N]  8 MB
    size_t o_dis  = o_xdh + (size_t)N_NODES * 8;              // float[N]  4 MB
    size_t o_part = o_dis + (size_t)N_NODES * 4;              // int[G1*NBK] 512 KB
    size_t o_eb   = o_part + (size_t)G1 * NBK * 4;
    size_t o_ec   = o_eb + NBK * 4;
    size_t need   = o_ec + NBK * 4;

    if (ws_size >= need) {
        unsigned* epair = (unsigned*)(ws + o_ep);
        uint2*    xdh   = (uint2*)(ws + o_xdh);
        float*    dis   = (float*)(ws + o_dis);
        int*      part  = (int*)(ws + o_part);
        int*      ebase = (int*)(ws + o_eb);
        int*      ecnt  = (int*)(ws + o_ec);

        k_hist<<<G1, T1, 0, stream>>>((const int4*)col, part, out, b2);
        k_colscan<<<NBK, 256, 0, stream>>>(part, ecnt);
        k_bscan<<<1, NBK, 0, stream>>>(ecnt, ebase);
        k_part<<<G1, T1, 0, stream>>>((const int4*)row, (const int4*)col, part, ebase, epair);
        k_deg2<<<NBUCK, 1024, 0, stream>>>(epair, ebase, ecnt, (const float4*)x, dis, xdh);
        k_accF<<<NBUCK, 1024, 0, stream>>>(epair, ebase, ecnt, xdh, dis, bat, W1, b1, W2, out);
    } else {
        int nb_n = (N_NODES + 255) / 256;
        int nb_e = (N_EDGES + 255) / 256;
        int*    deg = (int*)(ws);
        float*  dis = (float*)(ws + (size_t)N_NODES * 4);
        float*  s   = (float*)(ws + (size_t)N_NODES * 8);
        float4* s4  = (float4*)s;
        k_init<<<nb_n, 256, 0, stream>>>(deg, s4, out, b2);
        k_deg<<<nb_e, 256, 0, stream>>>(col, deg);
        k_dis<<<nb_n, 256, 0, stream>>>(deg, dis);
        k_scatter<<<nb_e, 256, 0, stream>>>(row, col, (const float4*)x, dis, s);
        k_node<<<nb_n, 256, 0, stream>>>((const float4*)x, s4, dis, bat, W1, b1, W2, out);
    }
}